// Round 1
// baseline (6997.149 us; speedup 1.0000x reference)
//
#include <hip/hip_runtime.h>

typedef __bf16 bf16x8 __attribute__((ext_vector_type(8)));
typedef float  f32x4  __attribute__((ext_vector_type(4)));
typedef short  s16x8  __attribute__((ext_vector_type(8)));

#define E_ 1024
#define T_ 1024
#define B_ 4
#define L_ 8
#define V_ 32000
#define M_ (B_*T_)   /* 4096 rows */

static __device__ __forceinline__ ushort f2bf(float f) {
  return __builtin_bit_cast(ushort, (__bf16)f);
}

// ---------------- weight cast f32 -> bf16 ----------------
__global__ __launch_bounds__(256) void castw_k(const float* __restrict__ in,
                                               ushort* __restrict__ out, int n) {
  int i = (blockIdx.x * 256 + threadIdx.x) * 8;
  if (i + 8 > n) return;
  float4 a = *(const float4*)(in + i);
  float4 b = *(const float4*)(in + i + 4);
  float v[8] = {a.x, a.y, a.z, a.w, b.x, b.y, b.z, b.w};
  union { s16x8 v; ushort u[8]; } pk;
  #pragma unroll
  for (int j = 0; j < 8; ++j) pk.u[j] = f2bf(v[j]);
  *(s16x8*)(out + i) = pk.v;
}

// ---------------- embedding ----------------
__global__ __launch_bounds__(256) void embed_k(const int* __restrict__ idx,
    const float* __restrict__ wte, const float* __restrict__ wpe,
    float* __restrict__ x) {
  int row = blockIdx.x;            // b*T + t
  int tok = idx[row];
  int t = row & (T_ - 1);
  int c = threadIdx.x;             // 256 float4 = 1024 floats
  float4 a = ((const float4*)(wte + (size_t)tok * E_))[c];
  float4 b = ((const float4*)(wpe + (size_t)t * E_))[c];
  float4 o; o.x = a.x + b.x; o.y = a.y + b.y; o.z = a.z + b.z; o.w = a.w + b.w;
  ((float4*)(x + (size_t)row * E_))[c] = o;
}

// ---------------- layernorm (f32 in, bf16 out) ----------------
__global__ __launch_bounds__(256) void ln_k(const float* __restrict__ x,
    const float* __restrict__ w, const float* __restrict__ b,
    ushort* __restrict__ out) {
  int row = blockIdx.x;
  int t = threadIdx.x;
  float4 v = ((const float4*)(x + (size_t)row * E_))[t];
  float s  = v.x + v.y + v.z + v.w;
  float s2 = v.x*v.x + v.y*v.y + v.z*v.z + v.w*v.w;
  #pragma unroll
  for (int o = 32; o > 0; o >>= 1) { s += __shfl_down(s, o); s2 += __shfl_down(s2, o); }
  __shared__ float sh[8];
  int wv = t >> 6;
  if ((t & 63) == 0) { sh[wv] = s; sh[4 + wv] = s2; }
  __syncthreads();
  s  = sh[0] + sh[1] + sh[2] + sh[3];
  s2 = sh[4] + sh[5] + sh[6] + sh[7];
  float mean = s * (1.f / E_);
  float var  = s2 * (1.f / E_) - mean * mean;
  float inv  = rsqrtf(var + 1e-5f);
  float4 wv4 = ((const float4*)w)[t];
  float4 bv4 = ((const float4*)b)[t];
  ushort* op = out + (size_t)row * E_ + t * 4;
  op[0] = f2bf((v.x - mean) * inv * wv4.x + bv4.x);
  op[1] = f2bf((v.y - mean) * inv * wv4.y + bv4.y);
  op[2] = f2bf((v.z - mean) * inv * wv4.z + bv4.z);
  op[3] = f2bf((v.w - mean) * inv * wv4.w + bv4.w);
}

// ---------------- GEMM: C[M,N] = A[M,K](bf16) @ W[N,K]^T(bf16) + bias ----------------
// EPI 0: outf = acc (+bias)
// EPI 1: outf = acc (+bias) + res   (residual)
// EPI 2: outh = bf16(gelu(acc+bias))
template<int EPI>
__global__ __launch_bounds__(256)
void gemm_bt(const ushort* __restrict__ A, const ushort* __restrict__ W,
             const float* __restrict__ bias, const float* __restrict__ res,
             float* __restrict__ outf, ushort* __restrict__ outh,
             int M, int N, int K) {
  __shared__ __align__(16) short As[128][40];
  __shared__ __align__(16) short Ws[128][40];
  int tid  = threadIdx.x;
  int bn   = blockIdx.x * 128;
  int bm   = blockIdx.y * 128;
  int wave = tid >> 6, lane = tid & 63;
  int wr = wave >> 1, wc = wave & 1;      // 2x2 wave grid, 64x64 each
  int g  = lane >> 4, lr = lane & 15;
  f32x4 acc[4][4] = {};
  int sr = tid >> 2;   // staging row 0..63
  int sc = tid & 3;    // 16B chunk

  for (int k0 = 0; k0 < K; k0 += 32) {
    #pragma unroll
    for (int it = 0; it < 2; ++it) {
      int r = sr + it * 64;
      s16x8 va = *(const s16x8*)(A + (size_t)(bm + r) * K + k0 + sc * 8);
      s16x8 vw = *(const s16x8*)(W + (size_t)(bn + r) * K + k0 + sc * 8);
      *(s16x8*)&As[r][sc * 8] = va;
      *(s16x8*)&Ws[r][sc * 8] = vw;
    }
    __syncthreads();
    bf16x8 af[4], bfr[4];
    #pragma unroll
    for (int f = 0; f < 4; ++f) {
      af[f]  = __builtin_bit_cast(bf16x8, *(const s16x8*)&As[wr * 64 + f * 16 + lr][g * 8]);
      bfr[f] = __builtin_bit_cast(bf16x8, *(const s16x8*)&Ws[wc * 64 + f * 16 + lr][g * 8]);
    }
    #pragma unroll
    for (int mf = 0; mf < 4; ++mf)
      #pragma unroll
      for (int nf = 0; nf < 4; ++nf)
        acc[mf][nf] = __builtin_amdgcn_mfma_f32_16x16x32_bf16(af[mf], bfr[nf], acc[mf][nf], 0, 0, 0);
    __syncthreads();
  }

  #pragma unroll
  for (int mf = 0; mf < 4; ++mf) {
    #pragma unroll
    for (int reg = 0; reg < 4; ++reg) {
      int row = bm + wr * 64 + mf * 16 + g * 4 + reg;
      #pragma unroll
      for (int nf = 0; nf < 4; ++nf) {
        int col = bn + wc * 64 + nf * 16 + lr;
        float v = acc[mf][nf][reg];
        if (bias) v += bias[col];
        if (EPI == 0) {
          outf[(size_t)row * N + col] = v;
        } else if (EPI == 1) {
          outf[(size_t)row * N + col] = v + res[(size_t)row * N + col];
        } else {
          float gl = 0.5f * v * (1.f + erff(v * 0.70710678118654752f));
          outh[(size_t)row * N + col] = f2bf(gl);
        }
      }
    }
  }
}

// ---------------- flash attention (VALU f32), causal ----------------
// grid: (B*H, T/64); block 256. thread t: row r=t/4 (of 64), d-seg s=t%4 (16 d's)
#define KB 32
__global__ __launch_bounds__(256) void attn_k(const float* __restrict__ qkv,
                                              ushort* __restrict__ y) {
  int bh = blockIdx.x;
  int b = bh >> 4, h = bh & 15;
  int qt = blockIdx.y;
  int tid = threadIdx.x;
  int r = tid >> 2;
  int s = tid & 3;
  int qrow = qt * 64 + r;
  const size_t E3 = 3 * E_;
  const float* base = qkv + (size_t)b * T_ * E3;

  float q[16];
  const float* qp = base + (size_t)qrow * E3 + h * 64 + s * 16;
  #pragma unroll
  for (int i = 0; i < 16; ++i) q[i] = qp[i] * 0.125f;

  float o[16];
  #pragma unroll
  for (int i = 0; i < 16; ++i) o[i] = 0.f;
  float mrun = -INFINITY, lrun = 0.f;

  __shared__ __align__(16) float Kb[KB][64];
  __shared__ __align__(16) float Vb[KB][64];

  int nkb = 2 * qt + 2;  // key blocks covering 0..qt*64+63
  for (int kb = 0; kb < nkb; ++kb) {
    #pragma unroll
    for (int it = 0; it < 2; ++it) {
      int idx = tid + it * 256;
      int j = idx >> 4, c = idx & 15;
      int krow = kb * KB + j;
      const float* kr = base + (size_t)krow * E3 + E_ + h * 64;
      const float* vr = base + (size_t)krow * E3 + 2 * E_ + h * 64;
      *(float4*)&Kb[j][c * 4] = ((const float4*)kr)[c];
      *(float4*)&Vb[j][c * 4] = ((const float4*)vr)[c];
    }
    __syncthreads();

    float sj[KB];
    #pragma unroll
    for (int j = 0; j < KB; ++j) {
      float p = 0.f;
      #pragma unroll
      for (int i = 0; i < 16; ++i) p += q[i] * Kb[j][s * 16 + i];
      p += __shfl_xor(p, 1);
      p += __shfl_xor(p, 2);
      sj[j] = (kb * KB + j <= qrow) ? p : -INFINITY;
    }
    float mb = sj[0];
    #pragma unroll
    for (int j = 1; j < KB; ++j) mb = fmaxf(mb, sj[j]);
    float mnew = fmaxf(mrun, mb);
    float corr = __expf(mrun - mnew);
    lrun *= corr;
    #pragma unroll
    for (int i = 0; i < 16; ++i) o[i] *= corr;
    #pragma unroll
    for (int j = 0; j < KB; ++j) {
      float p = __expf(sj[j] - mnew);
      lrun += p;
      #pragma unroll
      for (int i = 0; i < 16; ++i) o[i] += p * Vb[j][s * 16 + i];
    }
    mrun = mnew;
    __syncthreads();
  }
  float inv = 1.f / lrun;
  ushort* yp = y + (size_t)(b * T_ + qrow) * E_ + h * 64 + s * 16;
  #pragma unroll
  for (int i = 0; i < 16; ++i) yp[i] = f2bf(o[i] * inv);
}

// ---------------- orchestration ----------------
extern "C" void kernel_launch(void* const* d_in, const int* in_sizes, int n_in,
                              void* d_out, int out_size, void* d_ws, size_t ws_size,
                              hipStream_t stream) {
  const int*   idx   = (const int*)  d_in[0];
  const float* wte   = (const float*)d_in[1];
  const float* wpe   = (const float*)d_in[2];
  const float* ln1w  = (const float*)d_in[3];
  const float* ln1b  = (const float*)d_in[4];
  const float* attnw = (const float*)d_in[5];
  const float* attnb = (const float*)d_in[6];
  const float* projw = (const float*)d_in[7];
  const float* projb = (const float*)d_in[8];
  const float* ln2w  = (const float*)d_in[9];
  const float* ln2b  = (const float*)d_in[10];
  const float* fcw   = (const float*)d_in[11];
  const float* fcb   = (const float*)d_in[12];
  const float* fc2w  = (const float*)d_in[13];
  const float* fc2b  = (const float*)d_in[14];
  const float* lnfw  = (const float*)d_in[15];
  const float* lnfb  = (const float*)d_in[16];
  const float* lmw   = (const float*)d_in[17];
  float* out = (float*)d_out;

  char* p = (char*)d_ws;
  auto take = [&](size_t bytes) { char* r = p; p += (bytes + 255) & ~(size_t)255; return r; };
  ushort* wb_attn = (ushort*)take((size_t)L_ * 3 * E_ * E_ * 2);
  ushort* wb_proj = (ushort*)take((size_t)L_ * E_ * E_ * 2);
  ushort* wb_fc   = (ushort*)take((size_t)L_ * 4 * E_ * E_ * 2);
  ushort* wb_fc2  = (ushort*)take((size_t)L_ * E_ * 4 * E_ * 2);
  ushort* wb_lm   = (ushort*)take((size_t)V_ * E_ * 2);
  float*  x       = (float*) take((size_t)M_ * E_ * 4);
  ushort* hbuf    = (ushort*)take((size_t)M_ * E_ * 2);
  float*  qkv     = (float*) take((size_t)M_ * 3 * E_ * 4);
  ushort* ybuf    = (ushort*)take((size_t)M_ * E_ * 2);
  ushort* mlp     = (ushort*)take((size_t)M_ * 4 * E_ * 2);

  castw_k<<<(L_ * 3 * E_ * E_) / 2048, 256, 0, stream>>>(attnw, wb_attn, L_ * 3 * E_ * E_);
  castw_k<<<(L_ * E_ * E_) / 2048, 256, 0, stream>>>(projw, wb_proj, L_ * E_ * E_);
  castw_k<<<(L_ * 4 * E_ * E_) / 2048, 256, 0, stream>>>(fcw, wb_fc, L_ * 4 * E_ * E_);
  castw_k<<<(L_ * E_ * 4 * E_) / 2048, 256, 0, stream>>>(fc2w, wb_fc2, L_ * E_ * 4 * E_);
  castw_k<<<(V_ * E_) / 2048, 256, 0, stream>>>(lmw, wb_lm, V_ * E_);
  embed_k<<<M_, 256, 0, stream>>>(idx, wte, wpe, x);

  for (int l = 0; l < L_; ++l) {
    ln_k<<<M_, 256, 0, stream>>>(x, ln1w + l * E_, ln1b + l * E_, hbuf);
    gemm_bt<0><<<dim3(3 * E_ / 128, M_ / 128), 256, 0, stream>>>(
        hbuf, wb_attn + (size_t)l * 3 * E_ * E_, attnb + l * 3 * E_,
        nullptr, qkv, nullptr, M_, 3 * E_, E_);
    attn_k<<<dim3(B_ * 16, T_ / 64), 256, 0, stream>>>(qkv, ybuf);
    gemm_bt<1><<<dim3(E_ / 128, M_ / 128), 256, 0, stream>>>(
        ybuf, wb_proj + (size_t)l * E_ * E_, projb + l * E_,
        x, x, nullptr, M_, E_, E_);
    ln_k<<<M_, 256, 0, stream>>>(x, ln2w + l * E_, ln2b + l * E_, hbuf);
    gemm_bt<2><<<dim3(4 * E_ / 128, M_ / 128), 256, 0, stream>>>(
        hbuf, wb_fc + (size_t)l * 4 * E_ * E_, fcb + l * 4 * E_,
        nullptr, nullptr, mlp, M_, 4 * E_, E_);
    gemm_bt<1><<<dim3(E_ / 128, M_ / 128), 256, 0, stream>>>(
        mlp, wb_fc2 + (size_t)l * E_ * 4 * E_, fc2b + l * E_,
        x, x, nullptr, M_, E_, 4 * E_);
  }
  ln_k<<<M_, 256, 0, stream>>>(x, lnfw, lnfb, hbuf);
  gemm_bt<0><<<dim3(V_ / 128, M_ / 128), 256, 0, stream>>>(
      hbuf, wb_lm, nullptr, nullptr, out, nullptr, M_, V_, E_);
}

// Round 2
// 3723.694 us; speedup vs baseline: 1.8791x; 1.8791x over previous
//
#include <hip/hip_runtime.h>

typedef __bf16 bf16x8 __attribute__((ext_vector_type(8)));
typedef float  f32x4  __attribute__((ext_vector_type(4)));
typedef short  s16x8  __attribute__((ext_vector_type(8)));
typedef unsigned int u32;
#define AS1 __attribute__((address_space(1)))
#define AS3 __attribute__((address_space(3)))

#define E_ 1024
#define T_ 1024
#define B_ 4
#define L_ 8
#define V_ 32000
#define M_ (B_*T_)   /* 4096 rows */

static __device__ __forceinline__ ushort f2bf(float f) {
  return __builtin_bit_cast(ushort, (__bf16)f);
}

// ---------------- weight cast f32 -> bf16 ----------------
__global__ __launch_bounds__(256) void castw_k(const float* __restrict__ in,
                                               ushort* __restrict__ out, int n) {
  int i = (blockIdx.x * 256 + threadIdx.x) * 8;
  if (i + 8 > n) return;
  float4 a = *(const float4*)(in + i);
  float4 b = *(const float4*)(in + i + 4);
  float v[8] = {a.x, a.y, a.z, a.w, b.x, b.y, b.z, b.w};
  union { s16x8 v; ushort u[8]; } pk;
  #pragma unroll
  for (int j = 0; j < 8; ++j) pk.u[j] = f2bf(v[j]);
  *(s16x8*)(out + i) = pk.v;
}

// ---------------- embedding ----------------
__global__ __launch_bounds__(256) void embed_k(const int* __restrict__ idx,
    const float* __restrict__ wte, const float* __restrict__ wpe,
    float* __restrict__ x) {
  int row = blockIdx.x;            // b*T + t
  int tok = idx[row];
  int t = row & (T_ - 1);
  int c = threadIdx.x;             // 256 float4 = 1024 floats
  float4 a = ((const float4*)(wte + (size_t)tok * E_))[c];
  float4 b = ((const float4*)(wpe + (size_t)t * E_))[c];
  float4 o; o.x = a.x + b.x; o.y = a.y + b.y; o.z = a.z + b.z; o.w = a.w + b.w;
  ((float4*)(x + (size_t)row * E_))[c] = o;
}

// ---------------- layernorm (f32 in, bf16 out) ----------------
__global__ __launch_bounds__(256) void ln_k(const float* __restrict__ x,
    const float* __restrict__ w, const float* __restrict__ b,
    ushort* __restrict__ out) {
  int row = blockIdx.x;
  int t = threadIdx.x;
  float4 v = ((const float4*)(x + (size_t)row * E_))[t];
  float s  = v.x + v.y + v.z + v.w;
  float s2 = v.x*v.x + v.y*v.y + v.z*v.z + v.w*v.w;
  #pragma unroll
  for (int o = 32; o > 0; o >>= 1) { s += __shfl_down(s, o); s2 += __shfl_down(s2, o); }
  __shared__ float sh[8];
  int wv = t >> 6;
  if ((t & 63) == 0) { sh[wv] = s; sh[4 + wv] = s2; }
  __syncthreads();
  s  = sh[0] + sh[1] + sh[2] + sh[3];
  s2 = sh[4] + sh[5] + sh[6] + sh[7];
  float mean = s * (1.f / E_);
  float var  = s2 * (1.f / E_) - mean * mean;
  float inv  = rsqrtf(var + 1e-5f);
  float4 wv4 = ((const float4*)w)[t];
  float4 bv4 = ((const float4*)b)[t];
  ushort* op = out + (size_t)row * E_ + t * 4;
  op[0] = f2bf((v.x - mean) * inv * wv4.x + bv4.x);
  op[1] = f2bf((v.y - mean) * inv * wv4.y + bv4.y);
  op[2] = f2bf((v.z - mean) * inv * wv4.z + bv4.z);
  op[3] = f2bf((v.w - mean) * inv * wv4.w + bv4.w);
}

// ---------------- GEMM: C[M,N] = A[M,K](bf16) @ W[N,K]^T(bf16) + bias ----------------
// EPI 0: outf = acc (+bias)
// EPI 1: outf = acc (+bias) + res   (residual)
// EPI 2: outh = bf16(gelu(acc+bias))
// EPI 3: scatter to q (scaled, [BH,T,64]) / k ([BH,T,64]) / v^T ([BH,64,T]) bf16
template<int EPI>
__global__ __launch_bounds__(256)
void gemm_bt(const ushort* __restrict__ A, const ushort* __restrict__ W,
             const float* __restrict__ bias, const float* __restrict__ res,
             float* __restrict__ outf, ushort* __restrict__ outh,
             ushort* __restrict__ qb, ushort* __restrict__ kb, ushort* __restrict__ vb,
             int M, int N, int K) {
  __shared__ __align__(16) ushort As[128 * 32];
  __shared__ __align__(16) ushort Ws[128 * 32];
  int tid  = threadIdx.x;
  int bn   = blockIdx.x * 128;
  int bm   = blockIdx.y * 128;
  int wave = tid >> 6, lane = tid & 63;
  int wr = wave >> 1, wc = wave & 1;      // 2x2 wave grid, 64x64 each
  int g  = lane >> 4, lr = lane & 15;
  f32x4 acc[4][4] = {};
  int srow = lane >> 2;        // 0..15 row within 16-row chunk
  int scol = (lane & 3) * 8;   // ushort col (16B chunks)
  const ushort* Abase = A + (size_t)bm * K;
  const ushort* Wbase = W + (size_t)bn * K;

  for (int k0 = 0; k0 < K; k0 += 32) {
    #pragma unroll
    for (int it = 0; it < 2; ++it) {
      int rb = (wave * 2 + it) * 16;   // 16-row chunk base, covers 0..127
      __builtin_amdgcn_global_load_lds(
          (const AS1 u32*)(Abase + (size_t)(rb + srow) * K + k0 + scol),
          (AS3 u32*)&As[rb * 32], 16, 0, 0);
      __builtin_amdgcn_global_load_lds(
          (const AS1 u32*)(Wbase + (size_t)(rb + srow) * K + k0 + scol),
          (AS3 u32*)&Ws[rb * 32], 16, 0, 0);
    }
    __syncthreads();
    bf16x8 af[4], bfr[4];
    #pragma unroll
    for (int f = 0; f < 4; ++f) {
      af[f]  = __builtin_bit_cast(bf16x8, *(const s16x8*)&As[(wr * 64 + f * 16 + lr) * 32 + g * 8]);
      bfr[f] = __builtin_bit_cast(bf16x8, *(const s16x8*)&Ws[(wc * 64 + f * 16 + lr) * 32 + g * 8]);
    }
    #pragma unroll
    for (int mf = 0; mf < 4; ++mf)
      #pragma unroll
      for (int nf = 0; nf < 4; ++nf)
        acc[mf][nf] = __builtin_amdgcn_mfma_f32_16x16x32_bf16(af[mf], bfr[nf], acc[mf][nf], 0, 0, 0);
    __syncthreads();
  }

  #pragma unroll
  for (int mf = 0; mf < 4; ++mf) {
    #pragma unroll
    for (int reg = 0; reg < 4; ++reg) {
      int row = bm + wr * 64 + mf * 16 + g * 4 + reg;
      #pragma unroll
      for (int nf = 0; nf < 4; ++nf) {
        int col = bn + wc * 64 + nf * 16 + lr;
        float v = acc[mf][nf][reg];
        if (bias) v += bias[col];
        if (EPI == 0) {
          outf[(size_t)row * N + col] = v;
        } else if (EPI == 1) {
          outf[(size_t)row * N + col] = v + res[(size_t)row * N + col];
        } else if (EPI == 2) {
          float gl = 0.5f * v * (1.f + erff(v * 0.70710678118654752f));
          outh[(size_t)row * N + col] = f2bf(gl);
        } else {
          int b = row >> 10, t = row & 1023;
          int sec = col >> 10, cc = col & 1023;
          int h = cc >> 6, d = cc & 63;
          size_t bh = (size_t)(b * 16 + h);
          if (sec == 0)      qb[(bh * T_ + t) * 64 + d] = f2bf(v * 0.125f);
          else if (sec == 1) kb[(bh * T_ + t) * 64 + d] = f2bf(v);
          else               vb[(bh * 64 + d) * T_ + t] = f2bf(v);
        }
      }
    }
  }
}

// ---------------- MFMA flash attention, causal ----------------
// grid (B*H, T/64), block 256 (4 waves). Wave w: q rows qt*64+w*16 .. +15.
// Q,K: [BH][T][64] bf16 (Q pre-scaled), V: [BH][64][T] bf16 (transposed).
__global__ __launch_bounds__(256) void attn_k(const ushort* __restrict__ Qg,
    const ushort* __restrict__ Kg, const ushort* __restrict__ Vg,
    ushort* __restrict__ y) {
  int bh = blockIdx.x;       // b*16+h
  int qt = blockIdx.y;       // 0..15
  int tid = threadIdx.x, wave = tid >> 6, lane = tid & 63;
  int g = lane >> 4, lr = lane & 15;
  __shared__ __align__(16) ushort Ks[64 * 64];
  __shared__ __align__(16) ushort Vt[64 * 64];
  __shared__ __align__(16) ushort Ps[4][16 * 64];

  // Q fragments (A-operand layout): lane row lr, k-octet g within each 32-k step
  const ushort* qp = Qg + ((size_t)bh * T_ + qt * 64 + wave * 16 + lr) * 64;
  bf16x8 aq[2];
  aq[0] = __builtin_bit_cast(bf16x8, *(const s16x8*)(qp + 0 * 32 + g * 8));
  aq[1] = __builtin_bit_cast(bf16x8, *(const s16x8*)(qp + 1 * 32 + g * 8));

  f32x4 accO[4] = {};
  float m[4], l[4];
  #pragma unroll
  for (int r = 0; r < 4; ++r) { m[r] = -INFINITY; l[r] = 0.f; }

  int nkt = qt + 1;
  for (int kt = 0; kt < nkt; ++kt) {
    __syncthreads();
    // stage K tile [64 keys][64 d] and V^T tile [64 d][64 keys], XOR-swizzled
    #pragma unroll
    for (int it = 0; it < 2; ++it) {
      int c = tid + it * 256;          // 0..511 chunks of 8 ushort
      int row = c >> 3, co = (c & 7) * 8;
      int sidx = row * 64 + (co ^ ((row & 7) << 3));
      *(s16x8*)&Ks[sidx] = *(const s16x8*)(Kg + ((size_t)bh * T_ + kt * 64 + row) * 64 + co);
      *(s16x8*)&Vt[sidx] = *(const s16x8*)(Vg + ((size_t)(bh * 64 + row)) * T_ + kt * 64 + co);
    }
    __syncthreads();

    // S = Q K^T  (rows: q g*4+reg, cols: key nf*16+lr)
    f32x4 s[4] = {};
    #pragma unroll
    for (int ks = 0; ks < 2; ++ks)
      #pragma unroll
      for (int nf = 0; nf < 4; ++nf) {
        int krow = nf * 16 + lr;
        bf16x8 bk = __builtin_bit_cast(bf16x8,
            *(const s16x8*)&Ks[krow * 64 + ((ks * 32 + g * 8) ^ ((krow & 7) << 3))]);
        s[nf] = __builtin_amdgcn_mfma_f32_16x16x32_bf16(aq[ks], bk, s[nf], 0, 0, 0);
      }

    if (kt == qt) {  // diagonal tile: causal mask
      #pragma unroll
      for (int nf = 0; nf < 4; ++nf)
        #pragma unroll
        for (int reg = 0; reg < 4; ++reg) {
          int key = kt * 64 + nf * 16 + lr;
          int qr  = qt * 64 + wave * 16 + g * 4 + reg;
          if (key > qr) s[nf][reg] = -INFINITY;
        }
    }

    // row stats across 16-lane group
    float corr[4], psum[4];
    #pragma unroll
    for (int reg = 0; reg < 4; ++reg) {
      float v0 = fmaxf(fmaxf(s[0][reg], s[1][reg]), fmaxf(s[2][reg], s[3][reg]));
      #pragma unroll
      for (int msk = 1; msk <= 8; msk <<= 1) v0 = fmaxf(v0, __shfl_xor(v0, msk));
      float mnew = fmaxf(m[reg], v0);
      corr[reg] = __expf(m[reg] - mnew);
      m[reg] = mnew;
      psum[reg] = 0.f;
    }
    #pragma unroll
    for (int nf = 0; nf < 4; ++nf)
      #pragma unroll
      for (int reg = 0; reg < 4; ++reg) {
        float p = __expf(s[nf][reg] - m[reg]);
        psum[reg] += p;
        int prow = g * 4 + reg;
        Ps[wave][prow * 64 + ((nf * 16 + lr) ^ ((prow & 7) << 3))] = f2bf(p);
      }
    #pragma unroll
    for (int reg = 0; reg < 4; ++reg) {
      float t = psum[reg];
      #pragma unroll
      for (int msk = 1; msk <= 8; msk <<= 1) t += __shfl_xor(t, msk);
      l[reg] = l[reg] * corr[reg] + t;
      accO[0][reg] *= corr[reg]; accO[1][reg] *= corr[reg];
      accO[2][reg] *= corr[reg]; accO[3][reg] *= corr[reg];
    }

    // O += P V   (A = P rows lr; B = V^T rows d=nf*16+lr)
    #pragma unroll
    for (int ks = 0; ks < 2; ++ks) {
      bf16x8 ap = __builtin_bit_cast(bf16x8,
          *(const s16x8*)&Ps[wave][lr * 64 + ((ks * 32 + g * 8) ^ ((lr & 7) << 3))]);
      #pragma unroll
      for (int nf = 0; nf < 4; ++nf) {
        int drow = nf * 16 + lr;
        bf16x8 bv = __builtin_bit_cast(bf16x8,
            *(const s16x8*)&Vt[drow * 64 + ((ks * 32 + g * 8) ^ ((drow & 7) << 3))]);
        accO[nf] = __builtin_amdgcn_mfma_f32_16x16x32_bf16(ap, bv, accO[nf], 0, 0, 0);
      }
    }
  }

  int b = bh >> 4, h = bh & 15;
  float inv[4];
  #pragma unroll
  for (int reg = 0; reg < 4; ++reg) inv[reg] = 1.f / l[reg];
  #pragma unroll
  for (int nf = 0; nf < 4; ++nf)
    #pragma unroll
    for (int reg = 0; reg < 4; ++reg) {
      size_t row = (size_t)b * T_ + qt * 64 + wave * 16 + g * 4 + reg;
      y[row * E_ + h * 64 + nf * 16 + lr] = f2bf(accO[nf][reg] * inv[reg]);
    }
}

// ---------------- orchestration ----------------
extern "C" void kernel_launch(void* const* d_in, const int* in_sizes, int n_in,
                              void* d_out, int out_size, void* d_ws, size_t ws_size,
                              hipStream_t stream) {
  const int*   idx   = (const int*)  d_in[0];
  const float* wte   = (const float*)d_in[1];
  const float* wpe   = (const float*)d_in[2];
  const float* ln1w  = (const float*)d_in[3];
  const float* ln1b  = (const float*)d_in[4];
  const float* attnw = (const float*)d_in[5];
  const float* attnb = (const float*)d_in[6];
  const float* projw = (const float*)d_in[7];
  const float* projb = (const float*)d_in[8];
  const float* ln2w  = (const float*)d_in[9];
  const float* ln2b  = (const float*)d_in[10];
  const float* fcw   = (const float*)d_in[11];
  const float* fcb   = (const float*)d_in[12];
  const float* fc2w  = (const float*)d_in[13];
  const float* fc2b  = (const float*)d_in[14];
  const float* lnfw  = (const float*)d_in[15];
  const float* lnfb  = (const float*)d_in[16];
  const float* lmw   = (const float*)d_in[17];
  float* out = (float*)d_out;

  char* p = (char*)d_ws;
  auto take = [&](size_t bytes) { char* r = p; p += (bytes + 255) & ~(size_t)255; return r; };
  ushort* wb_attn = (ushort*)take((size_t)L_ * 3 * E_ * E_ * 2);
  ushort* wb_proj = (ushort*)take((size_t)L_ * E_ * E_ * 2);
  ushort* wb_fc   = (ushort*)take((size_t)L_ * 4 * E_ * E_ * 2);
  ushort* wb_fc2  = (ushort*)take((size_t)L_ * E_ * 4 * E_ * 2);
  ushort* wb_lm   = (ushort*)take((size_t)V_ * E_ * 2);
  float*  x       = (float*) take((size_t)M_ * E_ * 4);
  ushort* hbuf    = (ushort*)take((size_t)M_ * E_ * 2);
  ushort* qb      = (ushort*)take((size_t)B_ * 16 * T_ * 64 * 2);
  ushort* kbuf    = (ushort*)take((size_t)B_ * 16 * T_ * 64 * 2);
  ushort* vbuf    = (ushort*)take((size_t)B_ * 16 * T_ * 64 * 2);
  ushort* ybuf    = (ushort*)take((size_t)M_ * E_ * 2);
  ushort* mlp     = (ushort*)take((size_t)M_ * 4 * E_ * 2);

  castw_k<<<(L_ * 3 * E_ * E_) / 2048, 256, 0, stream>>>(attnw, wb_attn, L_ * 3 * E_ * E_);
  castw_k<<<(L_ * E_ * E_) / 2048, 256, 0, stream>>>(projw, wb_proj, L_ * E_ * E_);
  castw_k<<<(L_ * 4 * E_ * E_) / 2048, 256, 0, stream>>>(fcw, wb_fc, L_ * 4 * E_ * E_);
  castw_k<<<(L_ * E_ * 4 * E_) / 2048, 256, 0, stream>>>(fc2w, wb_fc2, L_ * E_ * 4 * E_);
  castw_k<<<(V_ * E_) / 2048, 256, 0, stream>>>(lmw, wb_lm, V_ * E_);
  embed_k<<<M_, 256, 0, stream>>>(idx, wte, wpe, x);

  for (int l = 0; l < L_; ++l) {
    ln_k<<<M_, 256, 0, stream>>>(x, ln1w + l * E_, ln1b + l * E_, hbuf);
    gemm_bt<3><<<dim3(3 * E_ / 128, M_ / 128), 256, 0, stream>>>(
        hbuf, wb_attn + (size_t)l * 3 * E_ * E_, attnb + l * 3 * E_,
        nullptr, nullptr, nullptr, qb, kbuf, vbuf, M_, 3 * E_, E_);
    attn_k<<<dim3(B_ * 16, T_ / 64), 256, 0, stream>>>(qb, kbuf, vbuf, ybuf);
    gemm_bt<1><<<dim3(E_ / 128, M_ / 128), 256, 0, stream>>>(
        ybuf, wb_proj + (size_t)l * E_ * E_, projb + l * E_,
        x, x, nullptr, nullptr, nullptr, nullptr, M_, E_, E_);
    ln_k<<<M_, 256, 0, stream>>>(x, ln2w + l * E_, ln2b + l * E_, hbuf);
    gemm_bt<2><<<dim3(4 * E_ / 128, M_ / 128), 256, 0, stream>>>(
        hbuf, wb_fc + (size_t)l * 4 * E_ * E_, fcb + l * 4 * E_,
        nullptr, nullptr, mlp, nullptr, nullptr, nullptr, M_, 4 * E_, E_);
    gemm_bt<1><<<dim3(E_ / 128, M_ / 128), 256, 0, stream>>>(
        mlp, wb_fc2 + (size_t)l * E_ * 4 * E_, fc2b + l * E_,
        x, x, nullptr, nullptr, nullptr, nullptr, M_, E_, 4 * E_);
  }
  ln_k<<<M_, 256, 0, stream>>>(x, lnfw, lnfb, hbuf);
  gemm_bt<0><<<dim3(V_ / 128, M_ / 128), 256, 0, stream>>>(
      hbuf, wb_lm, nullptr, nullptr, out, nullptr, nullptr, nullptr, nullptr, M_, V_, E_);
}

// Round 3
// 3645.624 us; speedup vs baseline: 1.9193x; 1.0214x over previous
//
#include <hip/hip_runtime.h>

typedef __bf16 bf16x8 __attribute__((ext_vector_type(8)));
typedef float  f32x4  __attribute__((ext_vector_type(4)));
typedef short  s16x8  __attribute__((ext_vector_type(8)));
typedef unsigned int u32;
#define AS1 __attribute__((address_space(1)))
#define AS3 __attribute__((address_space(3)))

#define E_ 1024
#define T_ 1024
#define B_ 4
#define L_ 8
#define V_ 32000
#define M_ (B_*T_)   /* 4096 rows */

static __device__ __forceinline__ ushort f2bf(float f) {
  return __builtin_bit_cast(ushort, (__bf16)f);
}

// ---------------- weight cast f32 -> bf16 ----------------
__global__ __launch_bounds__(256) void castw_k(const float* __restrict__ in,
                                               ushort* __restrict__ out, int n) {
  int i = (blockIdx.x * 256 + threadIdx.x) * 8;
  if (i + 8 > n) return;
  float4 a = *(const float4*)(in + i);
  float4 b = *(const float4*)(in + i + 4);
  float v[8] = {a.x, a.y, a.z, a.w, b.x, b.y, b.z, b.w};
  union { s16x8 v; ushort u[8]; } pk;
  #pragma unroll
  for (int j = 0; j < 8; ++j) pk.u[j] = f2bf(v[j]);
  *(s16x8*)(out + i) = pk.v;
}

// ---------------- embedding ----------------
__global__ __launch_bounds__(256) void embed_k(const int* __restrict__ idx,
    const float* __restrict__ wte, const float* __restrict__ wpe,
    float* __restrict__ x) {
  int row = blockIdx.x;
  int tok = idx[row];
  int t = row & (T_ - 1);
  int c = threadIdx.x;
  float4 a = ((const float4*)(wte + (size_t)tok * E_))[c];
  float4 b = ((const float4*)(wpe + (size_t)t * E_))[c];
  float4 o; o.x = a.x + b.x; o.y = a.y + b.y; o.z = a.z + b.z; o.w = a.w + b.w;
  ((float4*)(x + (size_t)row * E_))[c] = o;
}

// ---------------- layernorm (f32 in, bf16 out) ----------------
__global__ __launch_bounds__(256) void ln_k(const float* __restrict__ x,
    const float* __restrict__ w, const float* __restrict__ b,
    ushort* __restrict__ out) {
  int row = blockIdx.x;
  int t = threadIdx.x;
  float4 v = ((const float4*)(x + (size_t)row * E_))[t];
  float s  = v.x + v.y + v.z + v.w;
  float s2 = v.x*v.x + v.y*v.y + v.z*v.z + v.w*v.w;
  #pragma unroll
  for (int o = 32; o > 0; o >>= 1) { s += __shfl_down(s, o); s2 += __shfl_down(s2, o); }
  __shared__ float sh[8];
  int wv = t >> 6;
  if ((t & 63) == 0) { sh[wv] = s; sh[4 + wv] = s2; }
  __syncthreads();
  s  = sh[0] + sh[1] + sh[2] + sh[3];
  s2 = sh[4] + sh[5] + sh[6] + sh[7];
  float mean = s * (1.f / E_);
  float var  = s2 * (1.f / E_) - mean * mean;
  float inv  = rsqrtf(var + 1e-5f);
  float4 wv4 = ((const float4*)w)[t];
  float4 bv4 = ((const float4*)b)[t];
  ushort* op = out + (size_t)row * E_ + t * 4;
  op[0] = f2bf((v.x - mean) * inv * wv4.x + bv4.x);
  op[1] = f2bf((v.y - mean) * inv * wv4.y + bv4.y);
  op[2] = f2bf((v.z - mean) * inv * wv4.z + bv4.z);
  op[3] = f2bf((v.w - mean) * inv * wv4.w + bv4.w);
}

// ======================================================================
// 256x256 8-phase GEMM (T1+T2+T3+T4+T5). C = A[M,K] @ W[N,K]^T + bias.
// 512 threads = 8 waves (2 M x 4 N); BK=64; LDS 128KB (A,B x 2 slots x 2 bufs).
// EPI 0: outf=acc(+bias); EPI 2: outh=bf16(gelu); EPI 3: qkv scatter.
// ======================================================================
template<int BUF, int MH, int NH, int VM, typename F>
static __device__ __forceinline__ void phase8(
    const ushort (&AL)[32768], const ushort (&BL)[32768],
    int arow, int brow, int ca0, int ca1, f32x4 (&acc)[8][4], F&& stage) {
  bf16x8 av[4][2], bv[2][2];
  #pragma unroll
  for (int mfi = 0; mfi < 4; ++mfi) {
    av[mfi][0] = __builtin_bit_cast(bf16x8, *(const s16x8*)&AL[(BUF*2+MH)*8192 + arow + mfi*1024 + ca0]);
    av[mfi][1] = __builtin_bit_cast(bf16x8, *(const s16x8*)&AL[(BUF*2+MH)*8192 + arow + mfi*1024 + ca1]);
  }
  #pragma unroll
  for (int nfi = 0; nfi < 2; ++nfi) {
    bv[nfi][0] = __builtin_bit_cast(bf16x8, *(const s16x8*)&BL[(BUF*2+NH)*8192 + brow + nfi*1024 + ca0]);
    bv[nfi][1] = __builtin_bit_cast(bf16x8, *(const s16x8*)&BL[(BUF*2+NH)*8192 + brow + nfi*1024 + ca1]);
  }
  stage();
  asm volatile("s_barrier" ::: "memory");
  __builtin_amdgcn_s_setprio(1);
  #pragma unroll
  for (int mfi = 0; mfi < 4; ++mfi)
    #pragma unroll
    for (int nfi = 0; nfi < 2; ++nfi) {
      acc[MH*4+mfi][NH*2+nfi] = __builtin_amdgcn_mfma_f32_16x16x32_bf16(av[mfi][0], bv[nfi][0], acc[MH*4+mfi][NH*2+nfi], 0, 0, 0);
      acc[MH*4+mfi][NH*2+nfi] = __builtin_amdgcn_mfma_f32_16x16x32_bf16(av[mfi][1], bv[nfi][1], acc[MH*4+mfi][NH*2+nfi], 0, 0, 0);
    }
  __builtin_amdgcn_s_setprio(0);
  if (VM) asm volatile("s_waitcnt vmcnt(4)" ::: "memory");
  asm volatile("s_barrier" ::: "memory");
}

#define GLDS(src, dst) __builtin_amdgcn_global_load_lds((const AS1 u32*)(src), (AS3 u32*)(dst), 16, 0, 0)
#define STAGE_A(b, s, t) do { \
  GLDS(ap##s##_0 + (size_t)(t)*64, &AL[((b)*2+(s))*8192 + w*512]); \
  GLDS(ap##s##_1 + (size_t)(t)*64, &AL[((b)*2+(s))*8192 + 4096 + w*512]); } while(0)
#define STAGE_B(b, s, t) do { \
  GLDS(bp##s##_0 + (size_t)(t)*64, &BL[((b)*2+(s))*8192 + w*512]); \
  GLDS(bp##s##_1 + (size_t)(t)*64, &BL[((b)*2+(s))*8192 + 4096 + w*512]); } while(0)

template<int EPI>
__global__ __launch_bounds__(512, 2)
void gemm8(const ushort* __restrict__ A, const ushort* __restrict__ W,
           const float* __restrict__ bias,
           float* __restrict__ outf, ushort* __restrict__ outh,
           ushort* __restrict__ qb, ushort* __restrict__ kb, ushort* __restrict__ vb,
           int M, int N, int K, int gx) {
  __shared__ __align__(16) ushort AL[32768];
  __shared__ __align__(16) ushort BL[32768];
  int nwg = gridDim.x;
  int id  = blockIdx.x;
  int swz = (id & 7) * (nwg >> 3) + (id >> 3);   // XCD-chunked (nwg % 8 == 0)
  int bx = swz % gx, by = swz / gx;
  int bm = by * 256, bn = bx * 256;
  int tid = threadIdx.x;
  int w = tid >> 6, lane = tid & 63;
  int wm = w >> 2, wn = w & 3;
  int g = lane >> 4, lr = lane & 15;
  int sl8 = lane >> 3, sc = lane & 7;
  int cg8 = (sc ^ sl8) * 8;          // pre-swizzled source chunk (ushort offset)

  // stage source pointers: slot s, load j. A-slot s rows: j*128 + s*64 + r8
  int r0 = w * 8 + sl8;              // 0..63
  const ushort* ap0_0 = A + (size_t)(bm +       0 + r0) * K + cg8;
  const ushort* ap0_1 = A + (size_t)(bm + 128 + 0 + r0) * K + cg8;
  const ushort* ap1_0 = A + (size_t)(bm +      64 + r0) * K + cg8;
  const ushort* ap1_1 = A + (size_t)(bm + 128 + 64 + r0) * K + cg8;
  // B-slot s rows (srow = j*64 + r0): wn' = srow>>5, rr = srow&31
  int sr0 = r0, sr1 = 64 + r0;
  const ushort* bp0_0 = W + (size_t)(bn + (sr0 >> 5) * 64 +  0 + (sr0 & 31)) * K + cg8;
  const ushort* bp0_1 = W + (size_t)(bn + (sr1 >> 5) * 64 +  0 + (sr1 & 31)) * K + cg8;
  const ushort* bp1_0 = W + (size_t)(bn + (sr0 >> 5) * 64 + 32 + (sr0 & 31)) * K + cg8;
  const ushort* bp1_1 = W + (size_t)(bn + (sr1 >> 5) * 64 + 32 + (sr1 & 31)) * K + cg8;

  int NT = K >> 6;                   // 64-wide K tiles (even; >= 4)
  int NITER = NT >> 1;
  int arow = (wm * 64 + lr) * 64;
  int brow = (wn * 32 + lr) * 64;
  int ca0 = ((0 + g) ^ (lr & 7)) * 8;
  int ca1 = ((4 + g) ^ (lr & 7)) * 8;
  f32x4 acc[8][4] = {};

  // prologue: buf0 <- tile0 (all 4 slots), buf1 <- tile1 (A s0, B s0)
  STAGE_A(0, 0, 0); STAGE_A(0, 1, 0); STAGE_B(0, 0, 0); STAGE_B(0, 1, 0);
  STAGE_A(1, 0, 1); STAGE_B(1, 0, 1);
  asm volatile("s_waitcnt vmcnt(0)" ::: "memory");
  asm volatile("s_barrier" ::: "memory");

  for (int i = 0; i < NITER; ++i) {
    int t1 = 2 * i + 1;
    int t2 = 2 * i + 2; if (t2 > NT - 1) t2 = NT - 1;
    int t3 = 2 * i + 3; if (t3 > NT - 1) t3 = NT - 1;
    phase8<0,0,0,0>(AL, BL, arow, brow, ca0, ca1, acc, [&]{ STAGE_A(1, 1, t1); });
    phase8<0,0,1,0>(AL, BL, arow, brow, ca0, ca1, acc, [&]{ STAGE_B(1, 1, t1); });
    phase8<0,1,0,0>(AL, BL, arow, brow, ca0, ca1, acc, [&]{ STAGE_A(0, 0, t2); });
    phase8<0,1,1,1>(AL, BL, arow, brow, ca0, ca1, acc, [&]{ STAGE_B(0, 0, t2); });
    phase8<1,0,0,0>(AL, BL, arow, brow, ca0, ca1, acc, [&]{ STAGE_A(0, 1, t2); });
    phase8<1,0,1,0>(AL, BL, arow, brow, ca0, ca1, acc, [&]{ STAGE_B(0, 1, t2); });
    phase8<1,1,0,0>(AL, BL, arow, brow, ca0, ca1, acc, [&]{ STAGE_A(1, 0, t3); });
    phase8<1,1,1,1>(AL, BL, arow, brow, ca0, ca1, acc, [&]{ STAGE_B(1, 0, t3); });
  }

  #pragma unroll
  for (int mf = 0; mf < 8; ++mf) {
    #pragma unroll
    for (int reg = 0; reg < 4; ++reg) {
      int row = bm + wm * 128 + mf * 16 + g * 4 + reg;
      #pragma unroll
      for (int nf = 0; nf < 4; ++nf) {
        int col = bn + wn * 64 + nf * 16 + lr;
        float v = acc[mf][nf][reg];
        if (bias) v += bias[col];
        if (EPI == 0) {
          outf[(size_t)row * N + col] = v;
        } else if (EPI == 2) {
          float gl = 0.5f * v * (1.f + erff(v * 0.70710678118654752f));
          outh[(size_t)row * N + col] = f2bf(gl);
        } else {
          int b = row >> 10, t = row & 1023;
          int sec = col >> 10, cc = col & 1023;
          int h = cc >> 6, d = cc & 63;
          size_t bh = (size_t)(b * 16 + h);
          if (sec == 0)      qb[(bh * T_ + t) * 64 + d] = f2bf(v * 0.125f);
          else if (sec == 1) kb[(bh * T_ + t) * 64 + d] = f2bf(v);
          else               vb[(bh * 64 + d) * T_ + t] = f2bf(v);
        }
      }
    }
  }
}

// ---------------- 128x128 GEMM (kept for N=1024: proj, fc2) ----------------
// EPI 1: outf = acc + bias + res
template<int EPI>
__global__ __launch_bounds__(256)
void gemm_bt(const ushort* __restrict__ A, const ushort* __restrict__ W,
             const float* __restrict__ bias, const float* __restrict__ res,
             float* __restrict__ outf, ushort* __restrict__ outh,
             int M, int N, int K) {
  __shared__ __align__(16) ushort As[128 * 32];
  __shared__ __align__(16) ushort Ws[128 * 32];
  int tid  = threadIdx.x;
  int bn   = blockIdx.x * 128;
  int bm   = blockIdx.y * 128;
  int wave = tid >> 6, lane = tid & 63;
  int wr = wave >> 1, wc = wave & 1;
  int g  = lane >> 4, lr = lane & 15;
  f32x4 acc[4][4] = {};
  int srow = lane >> 2;
  int scol = (lane & 3) * 8;
  const ushort* Abase = A + (size_t)bm * K;
  const ushort* Wbase = W + (size_t)bn * K;

  for (int k0 = 0; k0 < K; k0 += 32) {
    #pragma unroll
    for (int it = 0; it < 2; ++it) {
      int rb = (wave * 2 + it) * 16;
      __builtin_amdgcn_global_load_lds(
          (const AS1 u32*)(Abase + (size_t)(rb + srow) * K + k0 + scol),
          (AS3 u32*)&As[rb * 32], 16, 0, 0);
      __builtin_amdgcn_global_load_lds(
          (const AS1 u32*)(Wbase + (size_t)(rb + srow) * K + k0 + scol),
          (AS3 u32*)&Ws[rb * 32], 16, 0, 0);
    }
    __syncthreads();
    bf16x8 af[4], bfr[4];
    #pragma unroll
    for (int f = 0; f < 4; ++f) {
      af[f]  = __builtin_bit_cast(bf16x8, *(const s16x8*)&As[(wr * 64 + f * 16 + lr) * 32 + g * 8]);
      bfr[f] = __builtin_bit_cast(bf16x8, *(const s16x8*)&Ws[(wc * 64 + f * 16 + lr) * 32 + g * 8]);
    }
    #pragma unroll
    for (int mf = 0; mf < 4; ++mf)
      #pragma unroll
      for (int nf = 0; nf < 4; ++nf)
        acc[mf][nf] = __builtin_amdgcn_mfma_f32_16x16x32_bf16(af[mf], bfr[nf], acc[mf][nf], 0, 0, 0);
    __syncthreads();
  }

  #pragma unroll
  for (int mf = 0; mf < 4; ++mf) {
    #pragma unroll
    for (int reg = 0; reg < 4; ++reg) {
      int row = bm + wr * 64 + mf * 16 + g * 4 + reg;
      #pragma unroll
      for (int nf = 0; nf < 4; ++nf) {
        int col = bn + wc * 64 + nf * 16 + lr;
        float v = acc[mf][nf][reg];
        if (bias) v += bias[col];
        if (EPI == 0) {
          outf[(size_t)row * N + col] = v;
        } else if (EPI == 1) {
          outf[(size_t)row * N + col] = v + res[(size_t)row * N + col];
        } else {
          float gl = 0.5f * v * (1.f + erff(v * 0.70710678118654752f));
          outh[(size_t)row * N + col] = f2bf(gl);
        }
      }
    }
  }
}

// ---------------- MFMA flash attention, causal ----------------
__global__ __launch_bounds__(256) void attn_k(const ushort* __restrict__ Qg,
    const ushort* __restrict__ Kg, const ushort* __restrict__ Vg,
    ushort* __restrict__ y) {
  int bh = blockIdx.x;
  int qt = blockIdx.y;
  int tid = threadIdx.x, wave = tid >> 6, lane = tid & 63;
  int g = lane >> 4, lr = lane & 15;
  __shared__ __align__(16) ushort Ks[64 * 64];
  __shared__ __align__(16) ushort Vt[64 * 64];
  __shared__ __align__(16) ushort Ps[4][16 * 64];

  const ushort* qp = Qg + ((size_t)bh * T_ + qt * 64 + wave * 16 + lr) * 64;
  bf16x8 aq[2];
  aq[0] = __builtin_bit_cast(bf16x8, *(const s16x8*)(qp + 0 * 32 + g * 8));
  aq[1] = __builtin_bit_cast(bf16x8, *(const s16x8*)(qp + 1 * 32 + g * 8));

  f32x4 accO[4] = {};
  float m[4], l[4];
  #pragma unroll
  for (int r = 0; r < 4; ++r) { m[r] = -INFINITY; l[r] = 0.f; }

  int nkt = qt + 1;
  for (int kt = 0; kt < nkt; ++kt) {
    __syncthreads();
    #pragma unroll
    for (int it = 0; it < 2; ++it) {
      int c = tid + it * 256;
      int row = c >> 3, co = (c & 7) * 8;
      int sidx = row * 64 + (co ^ ((row & 7) << 3));
      *(s16x8*)&Ks[sidx] = *(const s16x8*)(Kg + ((size_t)bh * T_ + kt * 64 + row) * 64 + co);
      *(s16x8*)&Vt[sidx] = *(const s16x8*)(Vg + ((size_t)(bh * 64 + row)) * T_ + kt * 64 + co);
    }
    __syncthreads();

    f32x4 s[4] = {};
    #pragma unroll
    for (int ks = 0; ks < 2; ++ks)
      #pragma unroll
      for (int nf = 0; nf < 4; ++nf) {
        int krow = nf * 16 + lr;
        bf16x8 bk = __builtin_bit_cast(bf16x8,
            *(const s16x8*)&Ks[krow * 64 + ((ks * 32 + g * 8) ^ ((krow & 7) << 3))]);
        s[nf] = __builtin_amdgcn_mfma_f32_16x16x32_bf16(aq[ks], bk, s[nf], 0, 0, 0);
      }

    if (kt == qt) {
      #pragma unroll
      for (int nf = 0; nf < 4; ++nf)
        #pragma unroll
        for (int reg = 0; reg < 4; ++reg) {
          int key = kt * 64 + nf * 16 + lr;
          int qr  = qt * 64 + wave * 16 + g * 4 + reg;
          if (key > qr) s[nf][reg] = -INFINITY;
        }
    }

    float corr[4], psum[4];
    #pragma unroll
    for (int reg = 0; reg < 4; ++reg) {
      float v0 = fmaxf(fmaxf(s[0][reg], s[1][reg]), fmaxf(s[2][reg], s[3][reg]));
      #pragma unroll
      for (int msk = 1; msk <= 8; msk <<= 1) v0 = fmaxf(v0, __shfl_xor(v0, msk));
      float mnew = fmaxf(m[reg], v0);
      corr[reg] = __expf(m[reg] - mnew);
      m[reg] = mnew;
      psum[reg] = 0.f;
    }
    #pragma unroll
    for (int nf = 0; nf < 4; ++nf)
      #pragma unroll
      for (int reg = 0; reg < 4; ++reg) {
        float p = __expf(s[nf][reg] - m[reg]);
        psum[reg] += p;
        int prow = g * 4 + reg;
        Ps[wave][prow * 64 + ((nf * 16 + lr) ^ ((prow & 7) << 3))] = f2bf(p);
      }
    #pragma unroll
    for (int reg = 0; reg < 4; ++reg) {
      float t = psum[reg];
      #pragma unroll
      for (int msk = 1; msk <= 8; msk <<= 1) t += __shfl_xor(t, msk);
      l[reg] = l[reg] * corr[reg] + t;
      accO[0][reg] *= corr[reg]; accO[1][reg] *= corr[reg];
      accO[2][reg] *= corr[reg]; accO[3][reg] *= corr[reg];
    }

    #pragma unroll
    for (int ks = 0; ks < 2; ++ks) {
      bf16x8 ap = __builtin_bit_cast(bf16x8,
          *(const s16x8*)&Ps[wave][lr * 64 + ((ks * 32 + g * 8) ^ ((lr & 7) << 3))]);
      #pragma unroll
      for (int nf = 0; nf < 4; ++nf) {
        int drow = nf * 16 + lr;
        bf16x8 bv = __builtin_bit_cast(bf16x8,
            *(const s16x8*)&Vt[drow * 64 + ((ks * 32 + g * 8) ^ ((drow & 7) << 3))]);
        accO[nf] = __builtin_amdgcn_mfma_f32_16x16x32_bf16(ap, bv, accO[nf], 0, 0, 0);
      }
    }
  }

  int b = bh >> 4, h = bh & 15;
  float inv[4];
  #pragma unroll
  for (int reg = 0; reg < 4; ++reg) inv[reg] = 1.f / l[reg];
  #pragma unroll
  for (int nf = 0; nf < 4; ++nf)
    #pragma unroll
    for (int reg = 0; reg < 4; ++reg) {
      size_t row = (size_t)b * T_ + qt * 64 + wave * 16 + g * 4 + reg;
      y[row * E_ + h * 64 + nf * 16 + lr] = f2bf(accO[nf][reg] * inv[reg]);
    }
}

// ---------------- orchestration ----------------
extern "C" void kernel_launch(void* const* d_in, const int* in_sizes, int n_in,
                              void* d_out, int out_size, void* d_ws, size_t ws_size,
                              hipStream_t stream) {
  const int*   idx   = (const int*)  d_in[0];
  const float* wte   = (const float*)d_in[1];
  const float* wpe   = (const float*)d_in[2];
  const float* ln1w  = (const float*)d_in[3];
  const float* ln1b  = (const float*)d_in[4];
  const float* attnw = (const float*)d_in[5];
  const float* attnb = (const float*)d_in[6];
  const float* projw = (const float*)d_in[7];
  const float* projb = (const float*)d_in[8];
  const float* ln2w  = (const float*)d_in[9];
  const float* ln2b  = (const float*)d_in[10];
  const float* fcw   = (const float*)d_in[11];
  const float* fcb   = (const float*)d_in[12];
  const float* fc2w  = (const float*)d_in[13];
  const float* fc2b  = (const float*)d_in[14];
  const float* lnfw  = (const float*)d_in[15];
  const float* lnfb  = (const float*)d_in[16];
  const float* lmw   = (const float*)d_in[17];
  float* out = (float*)d_out;

  char* p = (char*)d_ws;
  auto take = [&](size_t bytes) { char* r = p; p += (bytes + 255) & ~(size_t)255; return r; };
  ushort* wb_attn = (ushort*)take((size_t)L_ * 3 * E_ * E_ * 2);
  ushort* wb_proj = (ushort*)take((size_t)L_ * E_ * E_ * 2);
  ushort* wb_fc   = (ushort*)take((size_t)L_ * 4 * E_ * E_ * 2);
  ushort* wb_fc2  = (ushort*)take((size_t)L_ * E_ * 4 * E_ * 2);
  ushort* wb_lm   = (ushort*)take((size_t)V_ * E_ * 2);
  float*  x       = (float*) take((size_t)M_ * E_ * 4);
  ushort* hbuf    = (ushort*)take((size_t)M_ * E_ * 2);
  ushort* qb      = (ushort*)take((size_t)B_ * 16 * T_ * 64 * 2);
  ushort* kbuf    = (ushort*)take((size_t)B_ * 16 * T_ * 64 * 2);
  ushort* vbuf    = (ushort*)take((size_t)B_ * 16 * T_ * 64 * 2);
  ushort* ybuf    = (ushort*)take((size_t)M_ * E_ * 2);
  ushort* mlp     = (ushort*)take((size_t)M_ * 4 * E_ * 2);

  castw_k<<<(L_ * 3 * E_ * E_) / 2048, 256, 0, stream>>>(attnw, wb_attn, L_ * 3 * E_ * E_);
  castw_k<<<(L_ * E_ * E_) / 2048, 256, 0, stream>>>(projw, wb_proj, L_ * E_ * E_);
  castw_k<<<(L_ * 4 * E_ * E_) / 2048, 256, 0, stream>>>(fcw, wb_fc, L_ * 4 * E_ * E_);
  castw_k<<<(L_ * E_ * 4 * E_) / 2048, 256, 0, stream>>>(fc2w, wb_fc2, L_ * E_ * 4 * E_);
  castw_k<<<(V_ * E_) / 2048, 256, 0, stream>>>(lmw, wb_lm, V_ * E_);
  embed_k<<<M_, 256, 0, stream>>>(idx, wte, wpe, x);

  for (int l = 0; l < L_; ++l) {
    ln_k<<<M_, 256, 0, stream>>>(x, ln1w + l * E_, ln1b + l * E_, hbuf);
    gemm8<3><<<(3 * E_ / 256) * (M_ / 256), 512, 0, stream>>>(
        hbuf, wb_attn + (size_t)l * 3 * E_ * E_, attnb + l * 3 * E_,
        nullptr, nullptr, qb, kbuf, vbuf, M_, 3 * E_, E_, 3 * E_ / 256);
    attn_k<<<dim3(B_ * 16, T_ / 64), 256, 0, stream>>>(qb, kbuf, vbuf, ybuf);
    gemm_bt<1><<<dim3(E_ / 128, M_ / 128), 256, 0, stream>>>(
        ybuf, wb_proj + (size_t)l * E_ * E_, projb + l * E_,
        x, x, nullptr, M_, E_, E_);
    ln_k<<<M_, 256, 0, stream>>>(x, ln2w + l * E_, ln2b + l * E_, hbuf);
    gemm8<2><<<(4 * E_ / 256) * (M_ / 256), 512, 0, stream>>>(
        hbuf, wb_fc + (size_t)l * 4 * E_ * E_, fcb + l * 4 * E_,
        nullptr, mlp, nullptr, nullptr, nullptr, M_, 4 * E_, E_, 4 * E_ / 256);
    gemm_bt<1><<<dim3(E_ / 128, M_ / 128), 256, 0, stream>>>(
        mlp, wb_fc2 + (size_t)l * E_ * 4 * E_, fc2b + l * E_,
        x, x, nullptr, M_, E_, 4 * E_);
  }
  ln_k<<<M_, 256, 0, stream>>>(x, lnfw, lnfb, hbuf);
  gemm8<0><<<(V_ / 256) * (M_ / 256), 512, 0, stream>>>(
      hbuf, wb_lm, nullptr, out, nullptr, nullptr, nullptr, nullptr, M_, V_, E_, V_ / 256);
}